// Round 10
// baseline (790.574 us; speedup 1.0000x reference)
//
#include <hip/hip_runtime.h>
#include <hip/hip_bf16.h>

typedef __hip_bfloat16 bf16;
using bf16x8 = __attribute__((ext_vector_type(8))) short;   // MFMA A/B frag (4 VGPR)
using f32x4  = __attribute__((ext_vector_type(4))) float;   // MFMA C/D frag

#define Bn 4
#define Dm 512
#define Hh 8
#define V3 3
#define Lq 1024
#define NM (Bn*Hh*V3)   // 96 attention maps

#define WPITCH 144      // bf16 LDS row pitch in BYTES: 16B-aligned, bank-skewed

__device__ __forceinline__ unsigned short f2bf(float x) {
    bf16 h = __float2bfloat16(x);
    return *reinterpret_cast<unsigned short*>(&h);
}
__device__ __forceinline__ float bfbits2f(unsigned short u) {
    return __uint_as_float((unsigned)u << 16);
}

constexpr float SCALE = 0.57735026919f; // 1/sqrt(3)

// ---------------------------------------------------------------------------
// Kernel 0: split Wq/Wk/Wv/Wo into bf16 hi/lo once.
// Wsp layout (elems): matrix mi: hi at mi*524288, lo at mi*524288+262144.
// grid 1024 x 256.
// ---------------------------------------------------------------------------
__global__ __launch_bounds__(256) void split_w_kernel(
    const float* __restrict__ Wq, const float* __restrict__ Wk,
    const float* __restrict__ Wv, const float* __restrict__ Wo,
    unsigned short* __restrict__ Wsp)
{
    const int mi = blockIdx.x >> 8;
    const float* src = (mi == 0) ? Wq : (mi == 1) ? Wk : (mi == 2) ? Wv : Wo;
    const int idx = ((blockIdx.x & 255) << 8) + threadIdx.x;   // f4 index 0..65535
    float4 v4 = reinterpret_cast<const float4*>(src)[idx];
    float z[4] = {v4.x, v4.y, v4.z, v4.w};
    union { unsigned short u[4]; uint2 q; } hp, lp;
    #pragma unroll
    for (int e = 0; e < 4; ++e) {
        hp.u[e] = f2bf(z[e]);
        lp.u[e] = f2bf(z[e] - bfbits2f(hp.u[e]));
    }
    unsigned short* hi = Wsp + (size_t)mi * 524288;
    *reinterpret_cast<uint2*>(hi + (size_t)idx * 4)          = hp.q;
    *reinterpret_cast<uint2*>(hi + 262144 + (size_t)idx * 4) = lp.q;
}

// ---------------------------------------------------------------------------
// Kernel 1: ALL THREE projections via MFMA (split-bf16 3-term compensation).
// W staging = pure uint4 copy from pre-split Wsp (no per-block convert).
// ---------------------------------------------------------------------------
__global__ __launch_bounds__(256, 4) void proj_all_kernel(
    const float* __restrict__ xq, const float* __restrict__ xk,
    const float* __restrict__ xv,
    const unsigned short* __restrict__ Wsp,
    unsigned short* __restrict__ Qh, unsigned short* __restrict__ Ql,
    unsigned short* __restrict__ Kh, unsigned short* __restrict__ Kl,
    unsigned short* __restrict__ Vt)
{
    __shared__ unsigned char Wlds[2 * 64 * WPITCH];   // Wh | Wl, 18432 B
    unsigned char* LWh = Wlds;
    unsigned char* LWl = Wlds + 64 * WPITCH;

    const int fid = (blockIdx.z * gridDim.y + blockIdx.y) * gridDim.x + blockIdx.x;
    const int nid = (fid & 7) * 576 + (fid >> 3);
    const int x_  = nid & 15;          // l-block (16)
    const int y_  = (nid >> 4) & 7;    // e-block (8) == head
    const int zz  = nid >> 7;          // 0..35
    const int pid = zz / 12;           // 0=Q 1=K 2=V
    const int pl  = zz % 12;
    const int b   = pl / V3;
    const int v   = pl % V3;

    const float* xsrc = (pid == 0) ? xq : (pid == 1) ? xk : xv;
    const unsigned short* WhX = Wsp + (size_t)pid * 524288;
    const unsigned short* WlX = WhX + 262144;

    const int l0 = x_ * 64;
    const int e0 = y_ * 64;
    const int m  = (b * Hh + y_) * V3 + v;

    const int tid  = threadIdx.x;
    const int w    = tid >> 6;
    const int ln   = tid & 63;
    const int ln15 = ln & 15;
    const int lq   = ln >> 4;
    const int wl   = w * 16 + ln15;    // this lane's block-local l

    const float* xbase = xsrc + (size_t)b * Dm * V3 * Lq + (size_t)v * Lq + l0 + wl;

    f32x4 acc[4];
    #pragma unroll
    for (int i = 0; i < 4; ++i) acc[i] = (f32x4)0.f;

    for (int ph = 0; ph < 8; ++ph) {
        const int d0 = ph * 64;

        float xraw[16];
        #pragma unroll
        for (int kq = 0; kq < 2; ++kq)
            #pragma unroll
            for (int j = 0; j < 8; ++j)
                xraw[kq * 8 + j] =
                    xbase[(size_t)(d0 + kq * 32 + lq * 8 + j) * (V3 * Lq)];

        __syncthreads();
        // stage W tile hi/lo: pure copy, 16 KB, 4 uint4 per thread
        #pragma unroll
        for (int q2 = 0; q2 < 4; ++q2) {
            int idx = tid + q2 * 256;          // 0..1023
            const unsigned short* srcw = (idx < 512) ? WhX : WlX;
            unsigned char* dstw = (idx < 512) ? LWh : LWl;
            int i = idx & 511;
            int row = i >> 3, off = i & 7;
            uint4 d = *reinterpret_cast<const uint4*>(
                srcw + (size_t)(e0 + row) * Dm + d0 + off * 8);
            *reinterpret_cast<uint4*>(dstw + row * WPITCH + off * 16) = d;
        }
        __syncthreads();

        bf16x8 xh[2], xl[2];
        #pragma unroll
        for (int kq = 0; kq < 2; ++kq)
            #pragma unroll
            for (int j = 0; j < 8; ++j) {
                float xv_ = xraw[kq * 8 + j];
                unsigned short hs = f2bf(xv_);
                unsigned short ls = f2bf(xv_ - bfbits2f(hs));
                xh[kq][j] = (short)hs;
                xl[kq][j] = (short)ls;
            }

        #pragma unroll
        for (int lt = 0; lt < 4; ++lt) {
            int erow = lt * 16 + ln15;
            #pragma unroll
            for (int kq = 0; kq < 2; ++kq) {
                bf16x8 wh = *reinterpret_cast<const bf16x8*>(
                    LWh + erow * WPITCH + kq * 64 + lq * 16);
                bf16x8 wl_ = *reinterpret_cast<const bf16x8*>(
                    LWl + erow * WPITCH + kq * 64 + lq * 16);
                acc[lt] = __builtin_amdgcn_mfma_f32_16x16x32_bf16(wh,  xh[kq], acc[lt], 0, 0, 0);
                acc[lt] = __builtin_amdgcn_mfma_f32_16x16x32_bf16(wl_, xh[kq], acc[lt], 0, 0, 0);
                acc[lt] = __builtin_amdgcn_mfma_f32_16x16x32_bf16(wh,  xl[kq], acc[lt], 0, 0, 0);
            }
        }
    }

    if (pid < 2) {
        unsigned short* Oh_ = (pid == 0) ? Qh : Kh;
        unsigned short* Ol_ = (pid == 0) ? Ql : Kl;
        size_t rowbase = ((size_t)m * Lq + l0 + wl) * 64;
        #pragma unroll
        for (int lt = 0; lt < 4; ++lt) {
            union { unsigned short u[4]; uint2 v2; } hp, lp;
            #pragma unroll
            for (int r = 0; r < 4; ++r) {
                float y = acc[lt][r];
                hp.u[r] = f2bf(y);
                lp.u[r] = f2bf(y - bfbits2f(hp.u[r]));
            }
            *reinterpret_cast<uint2*>(Oh_ + rowbase + lt * 16 + lq * 4) = hp.v2;
            *reinterpret_cast<uint2*>(Ol_ + rowbase + lt * 16 + lq * 4) = lp.v2;
        }
    } else {
        #pragma unroll
        for (int lt = 0; lt < 4; ++lt)
            #pragma unroll
            for (int r = 0; r < 4; ++r) {
                int dd = lt * 16 + lq * 4 + r;
                Vt[(((size_t)(m * 64 + dd)) << 10) + l0 + wl] = f2bf(acc[lt][r]);
            }
    }
}

// ---------------------------------------------------------------------------
// Kernel 2: MFMA fused attention, two-pass, no-max softmax.
// 512-thread blocks; two 4-wave halves (rows l0b..+63 and +64..+127)
// SHARE the staged K-hi/K-lo/V tiles -> staging traffic halved.
// Q preload (FIXED vs R9): half0 hi->Lkh, half0 lo->Lkl,
// half1 hi->Lvt, half1 lo->Lp (all in-bounds; frags to regs before use).
// grid: 768 blocks (8 l-blocks x 96 maps), XCD-chunk swizzled (768 = 8*96).
// LDS 42.5 KiB, 2-3 blocks/CU.
// ---------------------------------------------------------------------------
__device__ __forceinline__ void stage512(
    unsigned char* dst, const unsigned short* __restrict__ src,
    size_t row_stride, int tid)
{
    int row = tid >> 3, off = tid & 7;       // 512 threads = 64 rows x 8 chunks
    uint4 d = *reinterpret_cast<const uint4*>(src + (size_t)row * row_stride + off * 8);
    *reinterpret_cast<uint4*>(dst + ((row * 128 + off * 16) ^ ((row & 7) << 4))) = d;
}

__global__ __launch_bounds__(512, 4) void fused_attn_kernel(
    const unsigned short* __restrict__ Qh, const unsigned short* __restrict__ Ql,
    const unsigned short* __restrict__ Kh, const unsigned short* __restrict__ Kl,
    const unsigned short* __restrict__ Vt, float* __restrict__ attn_out,
    unsigned short* __restrict__ Ot)
{
    __shared__ float4 ldsf4[2720];   // 43520 B
    unsigned char* L   = (unsigned char*)ldsf4;
    unsigned char* Lkh = L;            // 8 KiB  K-hi [s][dd]
    unsigned char* Lkl = L + 8192;     // 8 KiB  K-lo
    unsigned char* Lvt = L + 16384;    // 8 KiB  V^T [dd][s]
    unsigned char* Lp  = L + 24576;    // 16 KiB P bf16 [l][s], 8 KiB per half
    float* rowsumW = (float*)(L + 40960);   // [2][4][64]
    float* invrow  = (float*)(L + 43008);   // [128]

    const int fid = blockIdx.y * gridDim.x + blockIdx.x;
    const int nid = (fid & 7) * 96 + (fid >> 3);
    const int m   = nid >> 3;
    const int l0b = (nid & 7) * 128;

    const int tid  = threadIdx.x;        // 0..511
    const int hw   = tid >> 8;           // half 0/1 (waves 0-3 | 4-7)
    const int t8   = tid & 255;
    const int w    = t8 >> 6;            // wave within half
    const int ln   = tid & 63;
    const int ln15 = ln & 15;
    const int lq   = ln >> 4;
    const int sc   = w * 16;             // this wave's s-columns (QK)
    const int lh0  = l0b + hw * 64;      // this half's first q-row

    unsigned char* Lph = Lp + hw * 8192;

    // ---- preload Q fragments (hi+lo) for both halves via LDS bounce ----
    stage512(Lkh, Qh + ((size_t)m * Lq + l0b) * 64, 64, tid);        // half0 hi
    stage512(Lkl, Ql + ((size_t)m * Lq + l0b) * 64, 64, tid);        // half0 lo
    stage512(Lvt, Qh + ((size_t)m * Lq + l0b + 64) * 64, 64, tid);   // half1 hi
    stage512(Lp,  Ql + ((size_t)m * Lq + l0b + 64) * 64, 64, tid);   // half1 lo
    __syncthreads();
    const unsigned char* Lqh_ = hw ? Lvt : Lkh;
    const unsigned char* Lql_ = hw ? Lp  : Lkl;
    bf16x8 qfh[4][2], qfl[4][2];
    #pragma unroll
    for (int lt = 0; lt < 4; ++lt) {
        int row = lt * 16 + ln15;
        #pragma unroll
        for (int kq = 0; kq < 2; ++kq) {
            int byte = (row * 128 + kq * 64 + lq * 16) ^ ((row & 7) << 4);
            qfh[lt][kq] = *reinterpret_cast<const bf16x8*>(Lqh_ + byte);
            qfl[lt][kq] = *reinterpret_cast<const bf16x8*>(Lql_ + byte);
        }
    }
    __syncthreads();

    const size_t mbase = (size_t)m * Lq * Lq;
    const unsigned short* Khm = Kh + (size_t)m * Lq * 64;
    const unsigned short* Klm = Kl + (size_t)m * Lq * 64;
    const unsigned short* Vtm = Vt + (((size_t)m * 64) << 10);

    // ================= pass 1: row sums =================
    float lsum[4][4] = {};
    for (int s0 = 0; s0 < Lq; s0 += 64) {
        stage512(Lkh, Khm + (size_t)s0 * 64, 64, tid);
        stage512(Lkl, Klm + (size_t)s0 * 64, 64, tid);
        __syncthreads();
        bf16x8 bh[2], bl[2];
        #pragma unroll
        for (int kq = 0; kq < 2; ++kq) {
            int row = sc + ln15;
            int byte = (row * 128 + kq * 64 + lq * 16) ^ ((row & 7) << 4);
            bh[kq] = *reinterpret_cast<const bf16x8*>(Lkh + byte);
            bl[kq] = *reinterpret_cast<const bf16x8*>(Lkl + byte);
        }
        #pragma unroll
        for (int lt = 0; lt < 4; ++lt) {
            f32x4 c = (f32x4)0.f;
            #pragma unroll
            for (int kq = 0; kq < 2; ++kq) {
                c = __builtin_amdgcn_mfma_f32_16x16x32_bf16(qfh[lt][kq], bh[kq], c, 0, 0, 0);
                c = __builtin_amdgcn_mfma_f32_16x16x32_bf16(qfl[lt][kq], bh[kq], c, 0, 0, 0);
                c = __builtin_amdgcn_mfma_f32_16x16x32_bf16(qfh[lt][kq], bl[kq], c, 0, 0, 0);
            }
            #pragma unroll
            for (int r = 0; r < 4; ++r)
                lsum[lt][r] += __expf(c[r] * SCALE);
        }
        __syncthreads();
    }
    #pragma unroll
    for (int lt = 0; lt < 4; ++lt)
        #pragma unroll
        for (int r = 0; r < 4; ++r) {
            float vv = lsum[lt][r];
            vv += __shfl_xor(vv, 1);
            vv += __shfl_xor(vv, 2);
            vv += __shfl_xor(vv, 4);
            vv += __shfl_xor(vv, 8);
            if (ln15 == 0)
                rowsumW[(hw * 4 + w) * 64 + lt * 16 + lq * 4 + r] = vv;
        }
    __syncthreads();
    if (t8 < 64) {
        float* rs = rowsumW + hw * 256;
        invrow[hw * 64 + t8] = 1.0f /
            (rs[t8] + rs[64 + t8] + rs[128 + t8] + rs[192 + t8]);
    }
    __syncthreads();

    // ================= pass 2: attn write + PV =================
    f32x4 o[4];
    o[0] = (f32x4)0.f; o[1] = (f32x4)0.f; o[2] = (f32x4)0.f; o[3] = (f32x4)0.f;

    // cooperative attn-write geometry (per half): thread owns row t8>>2, 16 cols
    const int arow = t8 >> 2;
    const int acb  = (t8 & 3) * 32;
    const int aswz = (arow & 7) << 4;

    for (int s0 = 0; s0 < Lq; s0 += 64) {
        stage512(Lkh, Khm + (size_t)s0 * 64, 64, tid);
        stage512(Lkl, Klm + (size_t)s0 * 64, 64, tid);
        stage512(Lvt, Vtm + s0, 1024, tid);
        __syncthreads();
        bf16x8 bh[2], bl[2];
        #pragma unroll
        for (int kq = 0; kq < 2; ++kq) {
            int row = sc + ln15;
            int byte = (row * 128 + kq * 64 + lq * 16) ^ ((row & 7) << 4);
            bh[kq] = *reinterpret_cast<const bf16x8*>(Lkh + byte);
            bl[kq] = *reinterpret_cast<const bf16x8*>(Lkl + byte);
        }
        #pragma unroll
        for (int lt = 0; lt < 4; ++lt) {
            f32x4 c = (f32x4)0.f;
            #pragma unroll
            for (int kq = 0; kq < 2; ++kq) {
                c = __builtin_amdgcn_mfma_f32_16x16x32_bf16(qfh[lt][kq], bh[kq], c, 0, 0, 0);
                c = __builtin_amdgcn_mfma_f32_16x16x32_bf16(qfl[lt][kq], bh[kq], c, 0, 0, 0);
                c = __builtin_amdgcn_mfma_f32_16x16x32_bf16(qfh[lt][kq], bl[kq], c, 0, 0, 0);
            }
            #pragma unroll
            for (int r = 0; r < 4; ++r) {
                int l = lt * 16 + lq * 4 + r;          // local to half
                float p = __expf(c[r] * SCALE) * invrow[hw * 64 + l];
                int byte = (l * 128 + (sc + ln15) * 2) ^ ((l & 7) << 4);
                *reinterpret_cast<unsigned short*>(Lph + byte) = f2bf(p);
            }
        }
        __syncthreads();   // P visible within half; K reads done
        // PV
        {
            int prow = w * 16 + ln15;
            #pragma unroll
            for (int kq = 0; kq < 2; ++kq) {
                bf16x8 pa = *reinterpret_cast<const bf16x8*>(
                    Lph + ((prow * 128 + kq * 64 + lq * 16) ^ ((prow & 7) << 4)));
                #pragma unroll
                for (int nt = 0; nt < 4; ++nt) {
                    int vrow = nt * 16 + ln15;
                    bf16x8 vb = *reinterpret_cast<const bf16x8*>(
                        Lvt + ((vrow * 128 + kq * 64 + lq * 16) ^ ((vrow & 7) << 4)));
                    o[nt] = __builtin_amdgcn_mfma_f32_16x16x32_bf16(pa, vb, o[nt], 0, 0, 0);
                }
            }
        }
        // cooperative vectorized attn write (reads own half's Lp)
        {
            bf16x8 p0 = *reinterpret_cast<const bf16x8*>(
                Lph + ((arow * 128 + acb) ^ aswz));
            bf16x8 p1 = *reinterpret_cast<const bf16x8*>(
                Lph + ((arow * 128 + acb + 16) ^ aswz));
            float* dst = attn_out + mbase + (size_t)(lh0 + arow) * Lq + s0 + (t8 & 3) * 16;
            float4 f;
            f.x = bfbits2f((unsigned short)p0[0]);
            f.y = bfbits2f((unsigned short)p0[1]);
            f.z = bfbits2f((unsigned short)p0[2]);
            f.w = bfbits2f((unsigned short)p0[3]);
            *reinterpret_cast<float4*>(dst) = f;
            f.x = bfbits2f((unsigned short)p0[4]);
            f.y = bfbits2f((unsigned short)p0[5]);
            f.z = bfbits2f((unsigned short)p0[6]);
            f.w = bfbits2f((unsigned short)p0[7]);
            *reinterpret_cast<float4*>(dst + 4) = f;
            f.x = bfbits2f((unsigned short)p1[0]);
            f.y = bfbits2f((unsigned short)p1[1]);
            f.z = bfbits2f((unsigned short)p1[2]);
            f.w = bfbits2f((unsigned short)p1[3]);
            *reinterpret_cast<float4*>(dst + 8) = f;
            f.x = bfbits2f((unsigned short)p1[4]);
            f.y = bfbits2f((unsigned short)p1[5]);
            f.z = bfbits2f((unsigned short)p1[6]);
            f.w = bfbits2f((unsigned short)p1[7]);
            *reinterpret_cast<float4*>(dst + 12) = f;
        }
        __syncthreads();   // Lvt/Lp readers done; safe to restage
    }

    // ---- O epilogue: direct stores, NATURAL [m][l][dd] ----
    #pragma unroll
    for (int nt = 0; nt < 4; ++nt) {
        int dd = nt * 16 + ln15;
        #pragma unroll
        for (int r = 0; r < 4; ++r) {
            int l = w * 16 + lq * 4 + r;
            Ot[((size_t)m * Lq + lh0 + l) * 64 + dd] = f2bf(o[nt][r]);
        }
    }
}

// ---------------------------------------------------------------------------
// Kernel 3: MFMA output projection. Pure-copy Wo staging from Wsp.
// ---------------------------------------------------------------------------
__global__ __launch_bounds__(256, 4) void oproj_kernel(
    const unsigned short* __restrict__ Wsp, const unsigned short* __restrict__ Ot,
    float* __restrict__ out)
{
    __shared__ unsigned char Wlds[2 * 64 * WPITCH];
    unsigned char* LWh = Wlds;
    unsigned char* LWl = Wlds + 64 * WPITCH;

    const unsigned short* WhO = Wsp + (size_t)3 * 524288;
    const unsigned short* WlO = WhO + 262144;

    const int fid = (blockIdx.z * gridDim.y + blockIdx.y) * gridDim.x + blockIdx.x;
    const int nid = (fid & 7) * 192 + (fid >> 3);
    const int x_  = nid & 15;
    const int y_  = (nid >> 4) & 7;
    const int pl  = nid >> 7;
    const int b   = pl / V3;
    const int v   = pl % V3;

    const int l0 = x_ * 64;
    const int e0 = y_ * 64;

    const int tid  = threadIdx.x;
    const int w    = tid >> 6;
    const int ln   = tid & 63;
    const int ln15 = ln & 15;
    const int lq   = ln >> 4;
    const int wl   = w * 16 + ln15;

    f32x4 acc[4];
    #pragma unroll
    for (int i = 0; i < 4; ++i) acc[i] = (f32x4)0.f;

    for (int h = 0; h < Hh; ++h) {
        const int m = (b * Hh + h) * V3 + v;

        size_t obase = ((size_t)m * Lq + l0 + wl) * 64;
        bf16x8 ob0 = *reinterpret_cast<const bf16x8*>(Ot + obase + lq * 8);
        bf16x8 ob1 = *reinterpret_cast<const bf16x8*>(Ot + obase + 32 + lq * 8);

        __syncthreads();
        // stage Wo tile hi/lo: pure copy
        #pragma unroll
        for (int q2 = 0; q2 < 4; ++q2) {
            int idx = tid + q2 * 256;
            const unsigned short* srcw = (idx < 512) ? WhO : WlO;
            unsigned char* dstw = (idx < 512) ? LWh : LWl;
            int i = idx & 511;
            int row = i >> 3, off = i & 7;
            uint4 d = *reinterpret_cast<const uint4*>(
                srcw + (size_t)(e0 + row) * Dm + h * 64 + off * 8);
            *reinterpret_cast<uint4*>(dstw + row * WPITCH + off * 16) = d;
        }
        __syncthreads();

        #pragma unroll
        for (int lt = 0; lt < 4; ++lt) {
            int erow = lt * 16 + ln15;
            #pragma unroll
            for (int kq = 0; kq < 2; ++kq) {
                bf16x8 wh = *reinterpret_cast<const bf16x8*>(
                    LWh + erow * WPITCH + kq * 64 + lq * 16);
                bf16x8 wl_ = *reinterpret_cast<const bf16x8*>(
                    LWl + erow * WPITCH + kq * 64 + lq * 16);
                bf16x8 ob = kq ? ob1 : ob0;
                acc[lt] = __builtin_amdgcn_mfma_f32_16x16x32_bf16(wh,  ob, acc[lt], 0, 0, 0);
                acc[lt] = __builtin_amdgcn_mfma_f32_16x16x32_bf16(wl_, ob, acc[lt], 0, 0, 0);
            }
        }
    }

    #pragma unroll
    for (int lt = 0; lt < 4; ++lt)
        #pragma unroll
        for (int r = 0; r < 4; ++r) {
            int e = e0 + lt * 16 + lq * 4 + r;
            out[((size_t)(b * Dm + e) * V3 + v) * Lq + l0 + wl] = acc[lt][r];
        }
}

// ---------------------------------------------------------------------------
extern "C" void kernel_launch(void* const* d_in, const int* in_sizes, int n_in,
                              void* d_out, int out_size, void* d_ws, size_t ws_size,
                              hipStream_t stream)
{
    const float* q  = (const float*)d_in[0];
    const float* k  = (const float*)d_in[1];
    const float* vv = (const float*)d_in[2];
    const float* Wq = (const float*)d_in[3];
    const float* Wk = (const float*)d_in[4];
    const float* Wv = (const float*)d_in[5];
    const float* Wo = (const float*)d_in[6];

    float* out      = (float*)d_out;
    float* attn_out = out + (size_t)Bn * Dm * V3 * Lq;   // 6,291,456 elems in

    // workspace layout (bytes), bf16 buffers 12,582,912 B each:
    //   Qh 0 | Ql 12582912 | Kh 25165824 | Kl 37748736 | Vt 50331648 | Ot 62914560
    //   Wsp (pre-split weights, 4 MiB) at 75497472
    char* w = (char*)d_ws;
    unsigned short* Qh  = (unsigned short*)(w);
    unsigned short* Ql  = (unsigned short*)(w + 12582912);
    unsigned short* Kh  = (unsigned short*)(w + 25165824);
    unsigned short* Kl  = (unsigned short*)(w + 37748736);
    unsigned short* Vt  = (unsigned short*)(w + 50331648);
    unsigned short* Ot  = (unsigned short*)(w + 62914560);
    unsigned short* Wsp = (unsigned short*)(w + 75497472);

    dim3 b256(256);

    split_w_kernel<<<dim3(1024), b256, 0, stream>>>(Wq, Wk, Wv, Wo, Wsp);

    proj_all_kernel<<<dim3(16, 8, 36), b256, 0, stream>>>(
        q, k, vv, Wsp, Qh, Ql, Kh, Kl, Vt);

    fused_attn_kernel<<<dim3(8, NM), dim3(512), 0, stream>>>(
        Qh, Ql, Kh, Kl, Vt, attn_out, Ot);

    oproj_kernel<<<dim3(16, 8, 12), b256, 0, stream>>>(Wsp, Ot, out);
}

// Round 11
// 689.256 us; speedup vs baseline: 1.1470x; 1.1470x over previous
//
#include <hip/hip_runtime.h>
#include <hip/hip_bf16.h>

typedef __hip_bfloat16 bf16;
using bf16x8 = __attribute__((ext_vector_type(8))) short;   // MFMA A/B frag (4 VGPR)
using f32x4  = __attribute__((ext_vector_type(4))) float;   // MFMA C/D frag

#define Bn 4
#define Dm 512
#define Hh 8
#define V3 3
#define Lq 1024
#define NM (Bn*Hh*V3)   // 96 attention maps

#define WPITCH 144      // bf16 LDS row pitch in BYTES: 16B-aligned, bank-skewed

__device__ __forceinline__ unsigned short f2bf(float x) {
    bf16 h = __float2bfloat16(x);
    return *reinterpret_cast<unsigned short*>(&h);
}
__device__ __forceinline__ float bfbits2f(unsigned short u) {
    return __uint_as_float((unsigned)u << 16);
}

constexpr float SCALE = 0.57735026919f; // 1/sqrt(3)

// ---------------------------------------------------------------------------
// Kernel 0: split Wq/Wk/Wv/Wo into bf16 hi/lo once.  (R10-verified)
// Wsp layout (elems): matrix mi: hi at mi*524288, lo at mi*524288+262144.
// ---------------------------------------------------------------------------
__global__ __launch_bounds__(256) void split_w_kernel(
    const float* __restrict__ Wq, const float* __restrict__ Wk,
    const float* __restrict__ Wv, const float* __restrict__ Wo,
    unsigned short* __restrict__ Wsp)
{
    const int mi = blockIdx.x >> 8;
    const float* src = (mi == 0) ? Wq : (mi == 1) ? Wk : (mi == 2) ? Wv : Wo;
    const int idx = ((blockIdx.x & 255) << 8) + threadIdx.x;   // f4 index 0..65535
    float4 v4 = reinterpret_cast<const float4*>(src)[idx];
    float z[4] = {v4.x, v4.y, v4.z, v4.w};
    union { unsigned short u[4]; uint2 q; } hp, lp;
    #pragma unroll
    for (int e = 0; e < 4; ++e) {
        hp.u[e] = f2bf(z[e]);
        lp.u[e] = f2bf(z[e] - bfbits2f(hp.u[e]));
    }
    unsigned short* hi = Wsp + (size_t)mi * 524288;
    *reinterpret_cast<uint2*>(hi + (size_t)idx * 4)          = hp.q;
    *reinterpret_cast<uint2*>(hi + 262144 + (size_t)idx * 4) = lp.q;
}

// ---------------------------------------------------------------------------
// Kernel 1: ALL THREE projections via MFMA (split-bf16 3-term compensation).
// R10-verified: W staging = pure uint4 copy from pre-split Wsp.
// ---------------------------------------------------------------------------
__global__ __launch_bounds__(256, 4) void proj_all_kernel(
    const float* __restrict__ xq, const float* __restrict__ xk,
    const float* __restrict__ xv,
    const unsigned short* __restrict__ Wsp,
    unsigned short* __restrict__ Qh, unsigned short* __restrict__ Ql,
    unsigned short* __restrict__ Kh, unsigned short* __restrict__ Kl,
    unsigned short* __restrict__ Vt)
{
    __shared__ unsigned char Wlds[2 * 64 * WPITCH];   // Wh | Wl, 18432 B
    unsigned char* LWh = Wlds;
    unsigned char* LWl = Wlds + 64 * WPITCH;

    const int fid = (blockIdx.z * gridDim.y + blockIdx.y) * gridDim.x + blockIdx.x;
    const int nid = (fid & 7) * 576 + (fid >> 3);
    const int x_  = nid & 15;          // l-block (16)
    const int y_  = (nid >> 4) & 7;    // e-block (8) == head
    const int zz  = nid >> 7;          // 0..35
    const int pid = zz / 12;           // 0=Q 1=K 2=V
    const int pl  = zz % 12;
    const int b   = pl / V3;
    const int v   = pl % V3;

    const float* xsrc = (pid == 0) ? xq : (pid == 1) ? xk : xv;
    const unsigned short* WhX = Wsp + (size_t)pid * 524288;
    const unsigned short* WlX = WhX + 262144;

    const int l0 = x_ * 64;
    const int e0 = y_ * 64;
    const int m  = (b * Hh + y_) * V3 + v;

    const int tid  = threadIdx.x;
    const int w    = tid >> 6;
    const int ln   = tid & 63;
    const int ln15 = ln & 15;
    const int lq   = ln >> 4;
    const int wl   = w * 16 + ln15;    // this lane's block-local l

    const float* xbase = xsrc + (size_t)b * Dm * V3 * Lq + (size_t)v * Lq + l0 + wl;

    f32x4 acc[4];
    #pragma unroll
    for (int i = 0; i < 4; ++i) acc[i] = (f32x4)0.f;

    for (int ph = 0; ph < 8; ++ph) {
        const int d0 = ph * 64;

        float xraw[16];
        #pragma unroll
        for (int kq = 0; kq < 2; ++kq)
            #pragma unroll
            for (int j = 0; j < 8; ++j)
                xraw[kq * 8 + j] =
                    xbase[(size_t)(d0 + kq * 32 + lq * 8 + j) * (V3 * Lq)];

        __syncthreads();
        // stage W tile hi/lo: pure copy, 16 KB, 4 uint4 per thread
        #pragma unroll
        for (int q2 = 0; q2 < 4; ++q2) {
            int idx = tid + q2 * 256;          // 0..1023
            const unsigned short* srcw = (idx < 512) ? WhX : WlX;
            unsigned char* dstw = (idx < 512) ? LWh : LWl;
            int i = idx & 511;
            int row = i >> 3, off = i & 7;
            uint4 d = *reinterpret_cast<const uint4*>(
                srcw + (size_t)(e0 + row) * Dm + d0 + off * 8);
            *reinterpret_cast<uint4*>(dstw + row * WPITCH + off * 16) = d;
        }
        __syncthreads();

        bf16x8 xh[2], xl[2];
        #pragma unroll
        for (int kq = 0; kq < 2; ++kq)
            #pragma unroll
            for (int j = 0; j < 8; ++j) {
                float xv_ = xraw[kq * 8 + j];
                unsigned short hs = f2bf(xv_);
                unsigned short ls = f2bf(xv_ - bfbits2f(hs));
                xh[kq][j] = (short)hs;
                xl[kq][j] = (short)ls;
            }

        #pragma unroll
        for (int lt = 0; lt < 4; ++lt) {
            int erow = lt * 16 + ln15;
            #pragma unroll
            for (int kq = 0; kq < 2; ++kq) {
                bf16x8 wh = *reinterpret_cast<const bf16x8*>(
                    LWh + erow * WPITCH + kq * 64 + lq * 16);
                bf16x8 wl_ = *reinterpret_cast<const bf16x8*>(
                    LWl + erow * WPITCH + kq * 64 + lq * 16);
                acc[lt] = __builtin_amdgcn_mfma_f32_16x16x32_bf16(wh,  xh[kq], acc[lt], 0, 0, 0);
                acc[lt] = __builtin_amdgcn_mfma_f32_16x16x32_bf16(wl_, xh[kq], acc[lt], 0, 0, 0);
                acc[lt] = __builtin_amdgcn_mfma_f32_16x16x32_bf16(wh,  xl[kq], acc[lt], 0, 0, 0);
            }
        }
    }

    if (pid < 2) {
        unsigned short* Oh_ = (pid == 0) ? Qh : Kh;
        unsigned short* Ol_ = (pid == 0) ? Ql : Kl;
        size_t rowbase = ((size_t)m * Lq + l0 + wl) * 64;
        #pragma unroll
        for (int lt = 0; lt < 4; ++lt) {
            union { unsigned short u[4]; uint2 v2; } hp, lp;
            #pragma unroll
            for (int r = 0; r < 4; ++r) {
                float y = acc[lt][r];
                hp.u[r] = f2bf(y);
                lp.u[r] = f2bf(y - bfbits2f(hp.u[r]));
            }
            *reinterpret_cast<uint2*>(Oh_ + rowbase + lt * 16 + lq * 4) = hp.v2;
            *reinterpret_cast<uint2*>(Ol_ + rowbase + lt * 16 + lq * 4) = lp.v2;
        }
    } else {
        #pragma unroll
        for (int lt = 0; lt < 4; ++lt)
            #pragma unroll
            for (int r = 0; r < 4; ++r) {
                int dd = lt * 16 + lq * 4 + r;
                Vt[(((size_t)(m * 64 + dd)) << 10) + l0 + wl] = f2bf(acc[lt][r]);
            }
    }
}

// ---------------------------------------------------------------------------
// Kernel 2: MFMA fused attention — R6 champion version, VERBATIM.
// 256 threads, two-pass, no-max softmax; scalar attn writes; O natural.
// grid: dim3(16, 96) = 1536 blocks, XCD-chunk swizzled. LDS ~33 KiB.
// ---------------------------------------------------------------------------
__device__ __forceinline__ void stage_tile64(
    unsigned char* dst, const unsigned short* __restrict__ src,
    size_t row_stride, int tid)
{
    #pragma unroll
    for (int q = 0; q < 2; ++q) {
        int u = tid + q * 256;              // 512 units of 16B
        int row = u >> 3, off = u & 7;
        uint4 d = *reinterpret_cast<const uint4*>(src + (size_t)row * row_stride + off * 8);
        *reinterpret_cast<uint4*>(dst + ((row * 128 + off * 16) ^ ((row & 7) << 4))) = d;
    }
}

__global__ __launch_bounds__(256) void fused_attn_kernel(
    const unsigned short* __restrict__ Qh, const unsigned short* __restrict__ Ql,
    const unsigned short* __restrict__ Kh, const unsigned short* __restrict__ Kl,
    const unsigned short* __restrict__ Vt, float* __restrict__ attn_out,
    unsigned short* __restrict__ Ot)
{
    __shared__ float4 ldsf4[2128];   // 34048 B
    unsigned char* L   = (unsigned char*)ldsf4;
    unsigned char* Lkh = L;            // 8 KiB  K-hi [s][dd]
    unsigned char* Lkl = L + 8192;     // 8 KiB  K-lo
    unsigned char* Lvt = L + 16384;    // 8 KiB  V^T [dd][s]
    unsigned char* Lp  = L + 24576;    // 8 KiB  P bf16 [l][s]
    float* rowsumW = (float*)(L + 32768);   // [4][64]
    float* invrow  = (float*)(L + 33792);   // [64]

    const int fid = blockIdx.y * gridDim.x + blockIdx.x;
    const int nid = (fid & 7) * 192 + (fid >> 3);
    const int m  = nid >> 4;
    const int l0 = (nid & 15) * 64;

    const int tid = threadIdx.x;
    const int w    = tid >> 6;
    const int ln   = tid & 63;
    const int ln15 = ln & 15;
    const int lq   = ln >> 4;
    const int sc   = w * 16;          // this wave's s-columns (QK)

    // ---- preload Q fragments (hi+lo) into registers via LDS bounce ----
    stage_tile64(Lkh, Qh + ((size_t)m * Lq + l0) * 64, 64, tid);
    stage_tile64(Lkl, Ql + ((size_t)m * Lq + l0) * 64, 64, tid);
    __syncthreads();
    bf16x8 qfh[4][2], qfl[4][2];
    #pragma unroll
    for (int lt = 0; lt < 4; ++lt) {
        int row = lt * 16 + ln15;
        #pragma unroll
        for (int kq = 0; kq < 2; ++kq) {
            int byte = (row * 128 + kq * 64 + lq * 16) ^ ((row & 7) << 4);
            qfh[lt][kq] = *reinterpret_cast<const bf16x8*>(Lkh + byte);
            qfl[lt][kq] = *reinterpret_cast<const bf16x8*>(Lkl + byte);
        }
    }
    __syncthreads();

    const size_t mbase = (size_t)m * Lq * Lq;
    const unsigned short* Khm = Kh + (size_t)m * Lq * 64;
    const unsigned short* Klm = Kl + (size_t)m * Lq * 64;
    const unsigned short* Vtm = Vt + (((size_t)m * 64) << 10);

    // ================= pass 1: row sums =================
    float lsum[4][4] = {};
    for (int s0 = 0; s0 < Lq; s0 += 64) {
        stage_tile64(Lkh, Khm + (size_t)s0 * 64, 64, tid);
        stage_tile64(Lkl, Klm + (size_t)s0 * 64, 64, tid);
        __syncthreads();
        bf16x8 bh[2], bl[2];
        #pragma unroll
        for (int kq = 0; kq < 2; ++kq) {
            int row = sc + ln15;
            int byte = (row * 128 + kq * 64 + lq * 16) ^ ((row & 7) << 4);
            bh[kq] = *reinterpret_cast<const bf16x8*>(Lkh + byte);
            bl[kq] = *reinterpret_cast<const bf16x8*>(Lkl + byte);
        }
        #pragma unroll
        for (int lt = 0; lt < 4; ++lt) {
            f32x4 c = (f32x4)0.f;
            #pragma unroll
            for (int kq = 0; kq < 2; ++kq) {
                c = __builtin_amdgcn_mfma_f32_16x16x32_bf16(qfh[lt][kq], bh[kq], c, 0, 0, 0);
                c = __builtin_amdgcn_mfma_f32_16x16x32_bf16(qfl[lt][kq], bh[kq], c, 0, 0, 0);
                c = __builtin_amdgcn_mfma_f32_16x16x32_bf16(qfh[lt][kq], bl[kq], c, 0, 0, 0);
            }
            #pragma unroll
            for (int r = 0; r < 4; ++r)
                lsum[lt][r] += __expf(c[r] * SCALE);
        }
        __syncthreads();
    }
    #pragma unroll
    for (int lt = 0; lt < 4; ++lt)
        #pragma unroll
        for (int r = 0; r < 4; ++r) {
            float vv = lsum[lt][r];
            vv += __shfl_xor(vv, 1);
            vv += __shfl_xor(vv, 2);
            vv += __shfl_xor(vv, 4);
            vv += __shfl_xor(vv, 8);
            if (ln15 == 0) rowsumW[w * 64 + lt * 16 + lq * 4 + r] = vv;
        }
    __syncthreads();
    if (tid < 64)
        invrow[tid] = 1.0f / (rowsumW[tid] + rowsumW[64 + tid] +
                              rowsumW[128 + tid] + rowsumW[192 + tid]);
    __syncthreads();

    // ================= pass 2: attn write + PV =================
    f32x4 o[4];
    o[0] = (f32x4)0.f; o[1] = (f32x4)0.f; o[2] = (f32x4)0.f; o[3] = (f32x4)0.f;

    for (int s0 = 0; s0 < Lq; s0 += 64) {
        stage_tile64(Lkh, Khm + (size_t)s0 * 64, 64, tid);
        stage_tile64(Lkl, Klm + (size_t)s0 * 64, 64, tid);
        stage_tile64(Lvt, Vtm + s0, 1024, tid);
        __syncthreads();
        bf16x8 bh[2], bl[2];
        #pragma unroll
        for (int kq = 0; kq < 2; ++kq) {
            int row = sc + ln15;
            int byte = (row * 128 + kq * 64 + lq * 16) ^ ((row & 7) << 4);
            bh[kq] = *reinterpret_cast<const bf16x8*>(Lkh + byte);
            bl[kq] = *reinterpret_cast<const bf16x8*>(Lkl + byte);
        }
        #pragma unroll
        for (int lt = 0; lt < 4; ++lt) {
            f32x4 c = (f32x4)0.f;
            #pragma unroll
            for (int kq = 0; kq < 2; ++kq) {
                c = __builtin_amdgcn_mfma_f32_16x16x32_bf16(qfh[lt][kq], bh[kq], c, 0, 0, 0);
                c = __builtin_amdgcn_mfma_f32_16x16x32_bf16(qfl[lt][kq], bh[kq], c, 0, 0, 0);
                c = __builtin_amdgcn_mfma_f32_16x16x32_bf16(qfh[lt][kq], bl[kq], c, 0, 0, 0);
            }
            #pragma unroll
            for (int r = 0; r < 4; ++r) {
                int l = lt * 16 + lq * 4 + r;
                float p = __expf(c[r] * SCALE) * invrow[l];
                attn_out[mbase + (size_t)(l0 + l) * Lq + s0 + sc + ln15] = p;
                int byte = (l * 128 + (sc + ln15) * 2) ^ ((l & 7) << 4);
                *reinterpret_cast<unsigned short*>(Lp + byte) = f2bf(p);
            }
        }
        __syncthreads();   // P visible to all waves
        {
            int prow = w * 16 + ln15;   // PV A rows: this wave's l-strip
            #pragma unroll
            for (int kq = 0; kq < 2; ++kq) {
                bf16x8 pa = *reinterpret_cast<const bf16x8*>(
                    Lp + ((prow * 128 + kq * 64 + lq * 16) ^ ((prow & 7) << 4)));
                #pragma unroll
                for (int nt = 0; nt < 4; ++nt) {
                    int vrow = nt * 16 + ln15;
                    bf16x8 vb = *reinterpret_cast<const bf16x8*>(
                        Lvt + ((vrow * 128 + kq * 64 + lq * 16) ^ ((vrow & 7) << 4)));
                    o[nt] = __builtin_amdgcn_mfma_f32_16x16x32_bf16(pa, vb, o[nt], 0, 0, 0);
                }
            }
        }
        __syncthreads();   // PV reads done; safe to restage
    }

    // ---- O epilogue: direct stores, NATURAL [m][l][dd] ----
    #pragma unroll
    for (int nt = 0; nt < 4; ++nt) {
        int dd = nt * 16 + ln15;
        #pragma unroll
        for (int r = 0; r < 4; ++r) {
            int l = w * 16 + lq * 4 + r;
            Ot[((size_t)m * Lq + l0 + l) * 64 + dd] = f2bf(o[nt][r]);
        }
    }
}

// ---------------------------------------------------------------------------
// Kernel 3: MFMA output projection. R10-verified pure-copy Wo staging.
// ---------------------------------------------------------------------------
__global__ __launch_bounds__(256, 4) void oproj_kernel(
    const unsigned short* __restrict__ Wsp, const unsigned short* __restrict__ Ot,
    float* __restrict__ out)
{
    __shared__ unsigned char Wlds[2 * 64 * WPITCH];
    unsigned char* LWh = Wlds;
    unsigned char* LWl = Wlds + 64 * WPITCH;

    const unsigned short* WhO = Wsp + (size_t)3 * 524288;
    const unsigned short* WlO = WhO + 262144;

    const int fid = (blockIdx.z * gridDim.y + blockIdx.y) * gridDim.x + blockIdx.x;
    const int nid = (fid & 7) * 192 + (fid >> 3);
    const int x_  = nid & 15;
    const int y_  = (nid >> 4) & 7;
    const int pl  = nid >> 7;
    const int b   = pl / V3;
    const int v   = pl % V3;

    const int l0 = x_ * 64;
    const int e0 = y_ * 64;

    const int tid  = threadIdx.x;
    const int w    = tid >> 6;
    const int ln   = tid & 63;
    const int ln15 = ln & 15;
    const int lq   = ln >> 4;
    const int wl   = w * 16 + ln15;

    f32x4 acc[4];
    #pragma unroll
    for (int i = 0; i < 4; ++i) acc[i] = (f32x4)0.f;

    for (int h = 0; h < Hh; ++h) {
        const int m = (b * Hh + h) * V3 + v;

        size_t obase = ((size_t)m * Lq + l0 + wl) * 64;
        bf16x8 ob0 = *reinterpret_cast<const bf16x8*>(Ot + obase + lq * 8);
        bf16x8 ob1 = *reinterpret_cast<const bf16x8*>(Ot + obase + 32 + lq * 8);

        __syncthreads();
        // stage Wo tile hi/lo: pure copy
        #pragma unroll
        for (int q2 = 0; q2 < 4; ++q2) {
            int idx = tid + q2 * 256;
            const unsigned short* srcw = (idx < 512) ? WhO : WlO;
            unsigned char* dstw = (idx < 512) ? LWh : LWl;
            int i = idx & 511;
            int row = i >> 3, off = i & 7;
            uint4 d = *reinterpret_cast<const uint4*>(
                srcw + (size_t)(e0 + row) * Dm + h * 64 + off * 8);
            *reinterpret_cast<uint4*>(dstw + row * WPITCH + off * 16) = d;
        }
        __syncthreads();

        #pragma unroll
        for (int lt = 0; lt < 4; ++lt) {
            int erow = lt * 16 + ln15;
            #pragma unroll
            for (int kq = 0; kq < 2; ++kq) {
                bf16x8 wh = *reinterpret_cast<const bf16x8*>(
                    LWh + erow * WPITCH + kq * 64 + lq * 16);
                bf16x8 wl_ = *reinterpret_cast<const bf16x8*>(
                    LWl + erow * WPITCH + kq * 64 + lq * 16);
                bf16x8 ob = kq ? ob1 : ob0;
                acc[lt] = __builtin_amdgcn_mfma_f32_16x16x32_bf16(wh,  ob, acc[lt], 0, 0, 0);
                acc[lt] = __builtin_amdgcn_mfma_f32_16x16x32_bf16(wl_, ob, acc[lt], 0, 0, 0);
            }
        }
    }

    #pragma unroll
    for (int lt = 0; lt < 4; ++lt)
        #pragma unroll
        for (int r = 0; r < 4; ++r) {
            int e = e0 + lt * 16 + lq * 4 + r;
            out[((size_t)(b * Dm + e) * V3 + v) * Lq + l0 + wl] = acc[lt][r];
        }
}

// ---------------------------------------------------------------------------
extern "C" void kernel_launch(void* const* d_in, const int* in_sizes, int n_in,
                              void* d_out, int out_size, void* d_ws, size_t ws_size,
                              hipStream_t stream)
{
    const float* q  = (const float*)d_in[0];
    const float* k  = (const float*)d_in[1];
    const float* vv = (const float*)d_in[2];
    const float* Wq = (const float*)d_in[3];
    const float* Wk = (const float*)d_in[4];
    const float* Wv = (const float*)d_in[5];
    const float* Wo = (const float*)d_in[6];

    float* out      = (float*)d_out;
    float* attn_out = out + (size_t)Bn * Dm * V3 * Lq;   // 6,291,456 elems in

    // workspace layout (bytes), bf16 buffers 12,582,912 B each:
    //   Qh 0 | Ql 12582912 | Kh 25165824 | Kl 37748736 | Vt 50331648 | Ot 62914560
    //   Wsp (pre-split weights, 4 MiB) at 75497472
    char* w = (char*)d_ws;
    unsigned short* Qh  = (unsigned short*)(w);
    unsigned short* Ql  = (unsigned short*)(w + 12582912);
    unsigned short* Kh  = (unsigned short*)(w + 25165824);
    unsigned short* Kl  = (unsigned short*)(w + 37748736);
    unsigned short* Vt  = (unsigned short*)(w + 50331648);
    unsigned short* Ot  = (unsigned short*)(w + 62914560);
    unsigned short* Wsp = (unsigned short*)(w + 75497472);

    dim3 b256(256);

    split_w_kernel<<<dim3(1024), b256, 0, stream>>>(Wq, Wk, Wv, Wo, Wsp);

    proj_all_kernel<<<dim3(16, 8, 36), b256, 0, stream>>>(
        q, k, vv, Wsp, Qh, Ql, Kh, Kl, Vt);

    fused_attn_kernel<<<dim3(16, NM), b256, 0, stream>>>(
        Qh, Ql, Kh, Kl, Vt, attn_out, Ot);

    oproj_kernel<<<dim3(16, 8, 12), b256, 0, stream>>>(Wsp, Ot, out);
}